// Round 14
// baseline (311.147 us; speedup 1.0000x reference)
//
#include <hip/hip_runtime.h>
#include <math.h>

// LoRA-MLP, fp32 in/out. Fold rank-16 LoRA into weights (K=1), then two
// bf16 MFMA GEMMs: h = gelu(x@W1eff^T + b1); out = h@W2eff^T + b2.
#define M_ROWS 12608   // 64*197
#define D_DIM  768
#define H_DIM  3072

typedef __bf16 bf16_t;
typedef __bf16 bf16x8 __attribute__((ext_vector_type(8)));
typedef float  f32x4  __attribute__((ext_vector_type(4)));

// Fast GELU via sigmoid form of the tanh approximation (validated r6).
__device__ __forceinline__ float gelu_fast(float v) {
  float v2 = v * v;
  float z = v * fmaf(0.044715f, v2, 1.0f);
  float e = __expf(-1.5957691216057308f * z);
  return v * __builtin_amdgcn_rcpf(1.0f + e);
}

// Async global->LDS 16B copy. LDS dest must be wave-uniform base + lane*16.
__device__ __forceinline__ void gld16(const bf16_t* g, char* l) {
  __builtin_amdgcn_global_load_lds(
      (const __attribute__((address_space(1))) void*)g,
      (__attribute__((address_space(3))) void*)l, 16, 0, 0);
}

// ---------------------------------------------------------------------------
// Fused prep (R7-proven): ONE launch for {x cast, fold1, fold2}.
// ---------------------------------------------------------------------------
#define CAST_BLOCKS 9456
#define FOLD_BLOCKS 9216

__device__ __forceinline__ void fold_body(const float* __restrict__ W,
                                          const float* __restrict__ A,
                                          const float* __restrict__ Bm,
                                          bf16_t* __restrict__ Weff,
                                          int IN, long idx) {
  int o = (int)(idx / IN);
  int i = (int)(idx - (long)o * IN);
  float s = W[idx];
#pragma unroll
  for (int r = 0; r < 16; ++r)
    s += Bm[o * 16 + r] * A[r * IN + i];
  Weff[idx] = (bf16_t)s;
}

__global__ __launch_bounds__(256) void prep_kernel(
    const float* __restrict__ x, bf16_t* __restrict__ xb,
    const float* __restrict__ W1, const float* __restrict__ A1,
    const float* __restrict__ B1, bf16_t* __restrict__ W1eff,
    const float* __restrict__ W2, const float* __restrict__ A2,
    const float* __restrict__ B2, bf16_t* __restrict__ W2eff) {
  const int b = blockIdx.x;
  if (b < CAST_BLOCKS) {
    long i = ((long)b * 256 + threadIdx.x) * 4;
    float4 v = *(const float4*)(x + i);
    xb[i + 0] = (bf16_t)v.x; xb[i + 1] = (bf16_t)v.y;
    xb[i + 2] = (bf16_t)v.z; xb[i + 3] = (bf16_t)v.w;
  } else if (b < CAST_BLOCKS + FOLD_BLOCKS) {
    long idx = (long)(b - CAST_BLOCKS) * 256 + threadIdx.x;
    fold_body(W1, A1, B1, W1eff, D_DIM, idx);
  } else {
    long idx = (long)(b - CAST_BLOCKS - FOLD_BLOCKS) * 256 + threadIdx.x;
    fold_body(W2, A2, B2, W2eff, H_DIM, idx);
  }
}

// ---------------------------------------------------------------------------
// GEMM1 R14: m201-geometry 256x256 4-phase pipelined kernel.
// C = gelu(A@B^T + bias) -> bf16. BM=BN=256, BK=64; 8 waves 2Mx4N, wave
// tile 128x64 (24 ds_read : 64 MFMA per K-tile = 2.67, vs 2.0 at the pinned
// 128^2 kernel). 512 threads, LDS 128 KiB double-buffered.
// Buffer layout (64KB each): Ah0[128][64] @0, Ah1 @16K, Bh0 @32K, Bh1 @48K,
// proven 3-bit XOR swizzle on 128B rows (slot kk of row r holds global
// k-chunk kk^(r&7); 2-way = free; rule 21: linear gld16 dest + pre-swizzled
// global source -- NOT R5's broken 2-bit/64B-row variant).
// Phases p=(mq,ks): read af[4] (4 ds_read; +8 bf reads at p0), stage ONE
// unit of tile t+1 (2 gld16), setprio(1) 16 MFMA setprio(0).
// Stage units ordered by first-need: u0=Bh0(p0) u1=Bh1(p1) u2=A-rows0-63
// (p2) u3=A-rows64-127(p3). Derived waits (full outstanding-count timeline
// verified for prologue/steady/tail): end-p1 vmcnt(4) publishes u3 of
// CURRENT tile (needed p2); end-p3 vmcnt(2) publishes u0,u1,u2 of NEXT
// tile (needed next p0). 2 barriers/K-tile, never vmcnt(0) except tail.
// Rule 18: sched_barrier(0) after every inline-asm waitcnt.
// Grid 600 = 50 rbands x 12 cols, colb=bid/50: all XCDs share one B
// col-panel epoch (panel 393KB L2-resident), A streams.
// ---------------------------------------------------------------------------
__global__ __launch_bounds__(512, 2) void gemm1_kernel(
    const bf16_t* __restrict__ Amat, const bf16_t* __restrict__ Bmat,
    const float* __restrict__ bias, bf16_t* __restrict__ Cmat,
    int Mrows, int Ncols, int Kd) {
  __shared__ char smem[131072];
  bf16_t* lds = (bf16_t*)smem;
  float* sT = (float*)smem;      // epilogue scratch [64][256] f32, XOR

  const int colb = blockIdx.x / 50, rowb = blockIdx.x % 50;
  const int row0 = rowb * 256, col0 = colb * 256;

  const int tid = threadIdx.x, lane = tid & 63, wave = tid >> 6;
  const int wm = wave & 1, wn = wave >> 1;  // rows wm*128..+128, cols wn*64..+64

  // staging pointers: chunk c = tid + q*512; r = c>>3 in [0,128),
  // kkg = (c&7)^(r&7). gA[h][q]: rows row0+h*128+r; gB[h][q]: col0+h*128+r.
  const bf16_t* gA[2][2]; const bf16_t* gB[2][2];
  int ldsc[2];
#pragma unroll
  for (int q = 0; q < 2; ++q) {
    int c = tid + q * 512;
    int r = c >> 3, kkg = (c & 7) ^ (r & 7);
    ldsc[q] = c * 16;
#pragma unroll
    for (int h = 0; h < 2; ++h) {
      int ra = row0 + h * 128 + r; if (ra > Mrows - 1) ra = Mrows - 1;
      gA[h][q] = Amat + (size_t)ra * Kd + kkg * 8;
      gB[h][q] = Bmat + (size_t)(col0 + h * 128 + r) * Kd + kkg * 8;
    }
  }

  // fragment element-offsets within a half region (ks=0; ks toggles ^32).
  const int rl = lane & 15, kc = lane >> 4;
  const int abase0 = wm * 8192;               // this wave's A half
  const int bbase0 = 16384 + (wn >> 1) * 8192; // this wave's B half
  int aoffs[2][4], boffs[4];
#pragma unroll
  for (int mq = 0; mq < 2; ++mq)
#pragma unroll
    for (int i = 0; i < 4; ++i) {
      int rh = mq * 64 + i * 16 + rl;
      aoffs[mq][i] = rh * 64 + ((kc ^ (rh & 7)) * 8);
    }
#pragma unroll
  for (int i = 0; i < 4; ++i) {
    int rbl = (wn & 1) * 64 + i * 16 + rl;
    boffs[i] = rbl * 64 + ((kc ^ (rbl & 7)) * 8);
  }

  f32x4 acc[8][4] = {};
  const int NT = Kd / 64;   // 12

  // prologue: stage t0 units u0..u3 -> buf0; publish u0,u1,u2 (vmcnt(2)).
  gld16(gB[0][0], smem + 32768 + ldsc[0]); gld16(gB[0][1], smem + 32768 + ldsc[1]);
  gld16(gB[1][0], smem + 49152 + ldsc[0]); gld16(gB[1][1], smem + 49152 + ldsc[1]);
  gld16(gA[0][0], smem +     0 + ldsc[0]); gld16(gA[1][0], smem + 16384 + ldsc[0]);
  gld16(gA[0][1], smem +     0 + ldsc[1]); gld16(gA[1][1], smem + 16384 + ldsc[1]);
#pragma unroll
  for (int h = 0; h < 2; ++h)
#pragma unroll
    for (int q = 0; q < 2; ++q) { gA[h][q] += 64; gB[h][q] += 64; }
  asm volatile("s_waitcnt vmcnt(2)" ::: "memory");
  __builtin_amdgcn_sched_barrier(0);
  __builtin_amdgcn_s_barrier();

  for (int t = 0; t < NT; ++t) {
    const bool st = (t + 1 < NT);
    const int cb = (t & 1) * 32768;        // compute buffer (elements)
    const int sb = ((t + 1) & 1) * 65536;  // stage buffer (bytes)
    bf16x8 bf[4][2];
#pragma unroll
    for (int p = 0; p < 4; ++p) {
      const int mq = p >> 1, ks = p & 1;
      bf16x8 af[4];
#pragma unroll
      for (int i = 0; i < 4; ++i)
        af[i] = *(const bf16x8*)(lds + cb + abase0 + (aoffs[mq][i] ^ (ks * 32)));
      if (p == 0) {
#pragma unroll
        for (int k2 = 0; k2 < 2; ++k2)
#pragma unroll
          for (int i = 0; i < 4; ++i)
            bf[i][k2] = *(const bf16x8*)(lds + cb + bbase0 + (boffs[i] ^ (k2 * 32)));
      }
      if (st) {
        if (p == 0)      { gld16(gB[0][0], smem+sb+32768+ldsc[0]); gld16(gB[0][1], smem+sb+32768+ldsc[1]); gB[0][0]+=64; gB[0][1]+=64; }
        else if (p == 1) { gld16(gB[1][0], smem+sb+49152+ldsc[0]); gld16(gB[1][1], smem+sb+49152+ldsc[1]); gB[1][0]+=64; gB[1][1]+=64; }
        else if (p == 2) { gld16(gA[0][0], smem+sb+    0+ldsc[0]); gld16(gA[1][0], smem+sb+16384+ldsc[0]); gA[0][0]+=64; gA[1][0]+=64; }
        else             { gld16(gA[0][1], smem+sb+    0+ldsc[1]); gld16(gA[1][1], smem+sb+16384+ldsc[1]); gA[0][1]+=64; gA[1][1]+=64; }
      }
      __builtin_amdgcn_s_setprio(1);
#pragma unroll
      for (int i = 0; i < 4; ++i)
#pragma unroll
        for (int ni = 0; ni < 4; ++ni)
          acc[mq * 4 + i][ni] = __builtin_amdgcn_mfma_f32_16x16x32_bf16(
              af[i], bf[ni][ks], acc[mq * 4 + i][ni], 0, 0, 0);
      __builtin_amdgcn_s_setprio(0);
      if (p == 1) {
        if (st) { asm volatile("s_waitcnt vmcnt(4)" ::: "memory"); }
        else    { asm volatile("s_waitcnt vmcnt(0)" ::: "memory"); }
        __builtin_amdgcn_sched_barrier(0);
        __builtin_amdgcn_s_barrier();
      } else if (p == 3 && st) {
        asm volatile("s_waitcnt vmcnt(2)" ::: "memory");
        __builtin_amdgcn_sched_barrier(0);
        __builtin_amdgcn_s_barrier();
      }
    }
  }

  // epilogue: 4 passes of 64 rows x 256 cols. C/D lane layout: col=lane&15,
  // row=(lane>>4)*4+reg [m89-verified]. sT[64][256] f32, col ^ ((row&7)<<2)
  // (writes 2-way = free; read-side conflicts negligible at epilogue scale).
  __syncthreads();
  const int crow = (lane >> 4) * 4, ccol = lane & 15;
#pragma unroll
  for (int P = 0; P < 4; ++P) {
    if (wm == (P >> 1)) {
      const int mq = P & 1;
#pragma unroll
      for (int i = 0; i < 4; ++i)
#pragma unroll
        for (int ni = 0; ni < 4; ++ni)
#pragma unroll
          for (int r = 0; r < 4; ++r) {
            int srow = i * 16 + crow + r;
            int scol = wn * 64 + ni * 16 + ccol;
            sT[srow * 256 + (scol ^ ((srow & 7) << 2))] = acc[mq * 4 + i][ni][r];
          }
    }
    __syncthreads();
    {
      const int erow = tid >> 3, eseg = tid & 7;
      const int grow = row0 + P * 64 + erow;
      if (grow < Mrows) {
        const float* srow_p = sT + erow * 256;
        const float* bsrc = bias + col0 + eseg * 32;
        const int v = (erow & 7) << 2;
        bf16_t ov[32];
#pragma unroll
        for (int a = 0; a < 8; ++a) {
          const f32x4 q4 = *(const f32x4*)(srow_p + ((eseg * 32 + a * 4) ^ v));
#pragma unroll
          for (int b = 0; b < 4; ++b)
            ov[a * 4 + b] = (bf16_t)gelu_fast(q4[b] + bsrc[a * 4 + b]);
        }
        bf16_t* dst = Cmat + (size_t)grow * Ncols + col0 + eseg * 32;
#pragma unroll
        for (int k = 0; k < 4; ++k)
          *(bf16x8*)(dst + k * 8) = *(bf16x8*)(ov + k * 8);
      }
    }
    __syncthreads();
  }
}

// ---------------------------------------------------------------------------
// GEMM2 (R13-exact): 64x128 tile, BK=128, 2-phase gload_lds + 3-bit XOR
// swizzle on 256B rows. LDS 49152; lb(256,3). Grid 1200 = 8 XCD x 150.
// ---------------------------------------------------------------------------
__global__ __launch_bounds__(256, 3) void gemm2_kernel(
    const bf16_t* __restrict__ Amat, const bf16_t* __restrict__ Bmat,
    const float* __restrict__ bias, float* __restrict__ Cmat,
    int Mrows, int Ncols, int Kd) {
  __shared__ char smem[49152];
  bf16_t* lds = (bf16_t*)smem;   // A: elements [0,8192), B: [8192,24576)

  const int xcd = blockIdx.x & 7, t = blockIdx.x >> 3;   // t in [0,150)
  const int rowb = (t / 3) * 4 + (xcd & 3);
  if (rowb >= 197) return;
  const int colb = (xcd >> 2) * 3 + (t % 3);
  const int row0 = rowb * 64, col0 = colb * 128;

  const int tid = threadIdx.x, lane = tid & 63, wave = tid >> 6;
  const int wm = wave & 1, wn = wave >> 1;

  const bf16_t* gA[4]; int ldsA[4];
  const bf16_t* gB[8]; int ldsB[8];
#pragma unroll
  for (int q = 0; q < 4; ++q) {
    int c = tid + q * 256;
    int r = c >> 4, kkg = (c & 15) ^ (r & 7);
    gA[q] = Amat + (size_t)(row0 + r) * Kd + kkg * 8;
    ldsA[q] = c * 16;
  }
#pragma unroll
  for (int q = 0; q < 8; ++q) {
    int c = tid + q * 256;
    int r = c >> 4, kkg = (c & 15) ^ (r & 7);
    gB[q] = Bmat + (size_t)(col0 + r) * Kd + kkg * 8;
    ldsB[q] = 16384 + c * 16;
  }

  const int rl = lane & 15, kc = lane >> 4;
  int aoffs[2], boffs[4];
#pragma unroll
  for (int i = 0; i < 2; ++i) {
    int ra = wm * 32 + i * 16 + rl;
    aoffs[i] = ra * 128 + ((kc ^ (ra & 7)) * 8);
  }
#pragma unroll
  for (int i = 0; i < 4; ++i) {
    int rb = wn * 64 + i * 16 + rl;
    boffs[i] = 8192 + rb * 128 + ((kc ^ (rb & 7)) * 8);
  }

  f32x4 acc[2][4] = {};
  const int iters = Kd / 128;   // 24

#pragma unroll
  for (int q = 0; q < 4; ++q) { gld16(gA[q], smem + ldsA[q]); gA[q] += 128; }
#pragma unroll
  for (int q = 0; q < 8; ++q) { gld16(gB[q], smem + ldsB[q]); gB[q] += 128; }
  __syncthreads();

  for (int it = 0; it < iters; ++it) {
#pragma unroll
    for (int ks = 0; ks < 4; ++ks) {
      bf16x8 af[2], bfr[4];
#pragma unroll
      for (int i = 0; i < 2; ++i) af[i] = *(const bf16x8*)(lds + (aoffs[i] ^ (ks * 32)));
#pragma unroll
      for (int i = 0; i < 4; ++i) bfr[i] = *(const bf16x8*)(lds + (boffs[i] ^ (ks * 32)));
#pragma unroll
      for (int mi = 0; mi < 2; ++mi)
#pragma unroll
        for (int ni = 0; ni < 4; ++ni)
          acc[mi][ni] = __builtin_amdgcn_mfma_f32_16x16x32_bf16(
              af[mi], bfr[ni], acc[mi][ni], 0, 0, 0);
    }
    if (it + 1 < iters) {
      __syncthreads();
#pragma unroll
      for (int q = 0; q < 4; ++q) { gld16(gA[q], smem + ldsA[q]); gA[q] += 128; }
#pragma unroll
      for (int q = 0; q < 8; ++q) { gld16(gB[q], smem + ldsB[q]); gB[q] += 128; }
      __syncthreads();
    }
  }

  const int crow = (lane >> 4) * 4, ccol = lane & 15;
#pragma unroll
  for (int ni = 0; ni < 4; ++ni) {
    const int gc = col0 + wn * 64 + ni * 16 + ccol;
    const float bv = bias[gc];
#pragma unroll
    for (int mi = 0; mi < 2; ++mi) {
      const int gr = row0 + wm * 32 + mi * 16 + crow;
#pragma unroll
      for (int r = 0; r < 4; ++r)
        Cmat[(size_t)(gr + r) * Ncols + gc] = acc[mi][ni][r] + bv;
    }
  }
}

extern "C" void kernel_launch(void* const* d_in, const int* in_sizes, int n_in,
                              void* d_out, int out_size, void* d_ws, size_t ws_size,
                              hipStream_t stream) {
  const float* x  = (const float*)d_in[0];
  const float* W1 = (const float*)d_in[1];
  const float* b1 = (const float*)d_in[2];
  const float* A1 = (const float*)d_in[3];
  const float* B1 = (const float*)d_in[4];
  const float* W2 = (const float*)d_in[5];
  const float* b2 = (const float*)d_in[6];
  const float* A2 = (const float*)d_in[7];
  const float* B2 = (const float*)d_in[8];
  float* out = (float*)d_out;

  char* ws = (char*)d_ws;
  bf16_t* xb    = (bf16_t*)ws;                             // 19,365,888 B (pad)
  bf16_t* W1eff = (bf16_t*)(ws + 19366144);                //  4,718,592 B
  bf16_t* W2eff = (bf16_t*)(ws + 19366144 + 4718592);      //  4,718,592 B
  bf16_t* hbuf  = (bf16_t*)(ws + 19366144 + 2 * 4718592);  // 77,463,552 B

  // 1 launch: cast + fold1 + fold2
  prep_kernel<<<CAST_BLOCKS + 2 * FOLD_BLOCKS, 256, 0, stream>>>(
      x, xb, W1, A1, B1, W1eff, W2, A2, B2, W2eff);

  // GEMM1: 256x256 pipelined; grid 50 rbands x 12 cols = 600, 512 threads
  gemm1_kernel<<<600, 512, 0, stream>>>(
      xb, W1eff, b1, hbuf, M_ROWS, H_DIM, D_DIM);
  // GEMM2: 197 rbands x 6 cols; grid 8 XCD x 50 rband-strips x 3 cols = 1200
  gemm2_kernel<<<1200, 256, 0, stream>>>(
      hbuf, W2eff, b2, out, M_ROWS, D_DIM, H_DIM);
}

// Round 15
// 280.763 us; speedup vs baseline: 1.1082x; 1.1082x over previous
//
#include <hip/hip_runtime.h>
#include <math.h>

// LoRA-MLP, fp32 in/out. Fold rank-16 LoRA into weights (K=1), then two
// bf16 MFMA GEMMs: h = gelu(x@W1eff^T + b1); out = h@W2eff^T + b2.
// FINAL (R15 = R11-exact, session best 281.9us): 2-phase 128^2 gload_lds
// GEMM1 + 64x128 BK=64 GEMM2 + fused prep. Structural pipelining ports
// (R3/R5/R14) all regressed to 1 block/CU / MfmaUtil ~21%; the 2-phase
// template with ~4 blocks/CU inter-block overlap is the measured optimum
// reachable in this session.
#define M_ROWS 12608   // 64*197
#define D_DIM  768
#define H_DIM  3072

typedef __bf16 bf16_t;
typedef __bf16 bf16x8 __attribute__((ext_vector_type(8)));
typedef float  f32x4  __attribute__((ext_vector_type(4)));

// Fast GELU via sigmoid form of the tanh approximation (validated r6,
// absmax contribution ~3e-4 << threshold).
__device__ __forceinline__ float gelu_fast(float v) {
  float v2 = v * v;
  float z = v * fmaf(0.044715f, v2, 1.0f);
  float e = __expf(-1.5957691216057308f * z);
  return v * __builtin_amdgcn_rcpf(1.0f + e);
}

// Async global->LDS 16B copy. LDS dest must be wave-uniform base + lane*16.
__device__ __forceinline__ void gld16(const bf16_t* g, char* l) {
  __builtin_amdgcn_global_load_lds(
      (const __attribute__((address_space(1))) void*)g,
      (__attribute__((address_space(3))) void*)l, 16, 0, 0);
}

// ---------------------------------------------------------------------------
// Fused prep: ONE launch for {x cast, fold1, fold2} (independent work,
// whole blocks per branch).
//   blocks [0, 9456):      cast x (12608*768 f32 -> bf16), 4 elems/thread
//   blocks [9456, 18672):  W1eff = W1 + B1@A1  (3072x768)
//   blocks [18672, 27888): W2eff = W2 + B2@A2  (768x3072)
// 9456*1024 == 12608*768 and 9216*256 == 3072*768 exactly -> no guards.
// ---------------------------------------------------------------------------
#define CAST_BLOCKS 9456
#define FOLD_BLOCKS 9216

__device__ __forceinline__ void fold_body(const float* __restrict__ W,
                                          const float* __restrict__ A,
                                          const float* __restrict__ Bm,
                                          bf16_t* __restrict__ Weff,
                                          int IN, long idx) {
  int o = (int)(idx / IN);
  int i = (int)(idx - (long)o * IN);
  float s = W[idx];
#pragma unroll
  for (int r = 0; r < 16; ++r)
    s += Bm[o * 16 + r] * A[r * IN + i];
  Weff[idx] = (bf16_t)s;
}

__global__ __launch_bounds__(256) void prep_kernel(
    const float* __restrict__ x, bf16_t* __restrict__ xb,
    const float* __restrict__ W1, const float* __restrict__ A1,
    const float* __restrict__ B1, bf16_t* __restrict__ W1eff,
    const float* __restrict__ W2, const float* __restrict__ A2,
    const float* __restrict__ B2, bf16_t* __restrict__ W2eff) {
  const int b = blockIdx.x;
  if (b < CAST_BLOCKS) {
    long i = ((long)b * 256 + threadIdx.x) * 4;
    float4 v = *(const float4*)(x + i);
    xb[i + 0] = (bf16_t)v.x; xb[i + 1] = (bf16_t)v.y;
    xb[i + 2] = (bf16_t)v.z; xb[i + 3] = (bf16_t)v.w;
  } else if (b < CAST_BLOCKS + FOLD_BLOCKS) {
    long idx = (long)(b - CAST_BLOCKS) * 256 + threadIdx.x;
    fold_body(W1, A1, B1, W1eff, D_DIM, idx);
  } else {
    long idx = (long)(b - CAST_BLOCKS - FOLD_BLOCKS) * 256 + threadIdx.x;
    fold_body(W2, A2, B2, W2eff, H_DIM, idx);
  }
}

// ---------------------------------------------------------------------------
// GEMM1 (R11-exact, measured 88.5us / MfmaUtil 28.5 / VGPR 64 / LDS 32768):
// 128x128 2-phase gload_lds kernel, C = gelu(A@B^T + bias) -> bf16.
// Occupancy interventions exhausted (R8/R11: achieved ~34% regardless of
// LDS/lb headroom); structural pipelining regresses (R3/R5/R14: 1 block/CU,
// MfmaUtil ~21%). Pinned at ~672 TF -- the 2-phase template's measured
// optimum at this shape. DO NOT TOUCH.
// Main-loop XOR-swizzle: LDS slot kk of row r holds global k-chunk kk^(r&7)
// (3-bit involution on 128B rows -> 2-way bank aliasing = free; rule 21:
// linear gld16 dest + pre-swizzled global source).
// SCHED: per XCD sweep rbands fast per col (A-band L2-resident).
// ---------------------------------------------------------------------------
__global__ __launch_bounds__(256, 4) void gemm1_kernel(
    const bf16_t* __restrict__ Amat, const bf16_t* __restrict__ Bmat,
    const float* __restrict__ bias, bf16_t* __restrict__ Cmat,
    int Mrows, int Ncols, int Kd) {
  __shared__ char smem[32768];
  bf16_t* lds = (bf16_t*)smem;   // A: elements [0,8192), B: [8192,16384)
  float* sT = (float*)smem;      // GELU epilogue scratch [64][128] f32, XOR

  const int xcd = blockIdx.x & 7, t = blockIdx.x >> 3;
  const int colb = t / 13;
  const int rowb = (t % 13) * 8 + xcd;
  if (rowb >= 99) return;
  const int row0 = rowb * 128, col0 = colb * 128;

  const int tid = threadIdx.x, lane = tid & 63, wave = tid >> 6;
  const int wm = wave & 1, wn = wave >> 1;

  const bf16_t* gA[4]; const bf16_t* gB[4];
  int ldsA[4], ldsB[4];
#pragma unroll
  for (int q = 0; q < 4; ++q) {
    int c = tid + q * 256;
    int r = c >> 3, kkg = (c & 7) ^ (r & 7);
    int ra = row0 + r; if (ra > Mrows - 1) ra = Mrows - 1;  // M-edge clamp
    gA[q] = Amat + (size_t)ra * Kd + kkg * 8;
    gB[q] = Bmat + (size_t)(col0 + r) * Kd + kkg * 8;
    ldsA[q] = c * 16;
    ldsB[q] = 16384 + c * 16;
  }

  const int rl = lane & 15, kc = lane >> 4;
  int aoffs[4], boffs[4];
#pragma unroll
  for (int i = 0; i < 4; ++i) {
    int ra = wm * 64 + i * 16 + rl;
    int rb = wn * 64 + i * 16 + rl;
    aoffs[i] = ra * 64 + ((kc ^ (ra & 7)) * 8);
    boffs[i] = 8192 + rb * 64 + ((kc ^ (rb & 7)) * 8);
  }

  f32x4 acc[4][4] = {};
  const int iters = Kd / 64;

#pragma unroll
  for (int q = 0; q < 4; ++q) {
    gld16(gA[q], smem + ldsA[q]);
    gld16(gB[q], smem + ldsB[q]);
    gA[q] += 64; gB[q] += 64;
  }
  __syncthreads();

  for (int it = 0; it < iters; ++it) {
#pragma unroll
    for (int ks = 0; ks < 2; ++ks) {
      bf16x8 af[4], bfr[4];
#pragma unroll
      for (int i = 0; i < 4; ++i) af[i] = *(const bf16x8*)(lds + (aoffs[i] ^ (ks * 32)));
#pragma unroll
      for (int i = 0; i < 4; ++i) bfr[i] = *(const bf16x8*)(lds + (boffs[i] ^ (ks * 32)));
#pragma unroll
      for (int mi = 0; mi < 4; ++mi)
#pragma unroll
        for (int ni = 0; ni < 4; ++ni)
          acc[mi][ni] = __builtin_amdgcn_mfma_f32_16x16x32_bf16(
              af[mi], bfr[ni], acc[mi][ni], 0, 0, 0);
    }
    if (it + 1 < iters) {
      __syncthreads();
#pragma unroll
      for (int q = 0; q < 4; ++q) {
        gld16(gA[q], smem + ldsA[q]);
        gld16(gB[q], smem + ldsB[q]);
        gA[q] += 64; gB[q] += 64;
      }
      __syncthreads();
    }
  }

  // epilogue. C/D lane layout: col=lane&15, row=(lane>>4)*4+reg [m89-verified]
  // sT[64][128] f32 with physical col = logical ^ ((row&7)<<2).
  const int crow = (lane >> 4) * 4, ccol = lane & 15;
  __syncthreads();
#pragma unroll
  for (int p = 0; p < 2; ++p) {
#pragma unroll
    for (int s = 0; s < 2; ++s) {
      int mi = 2 * p + s;
#pragma unroll
      for (int ni = 0; ni < 4; ++ni)
#pragma unroll
        for (int r = 0; r < 4; ++r) {
          int rr = wm * 32 + s * 16 + crow + r;
          sT[rr * 128 + ((wn * 64 + ni * 16 + ccol) ^ ((rr & 7) << 2))] =
              acc[mi][ni][r];
        }
    }
    __syncthreads();
    const int erow = tid >> 2, eseg = tid & 3;
    const int grow = row0 + (erow >> 5) * 64 + (2 * p + ((erow >> 4) & 1)) * 16 + (erow & 15);
    if (grow < Mrows) {
      const float* srow = sT + erow * 128;
      const float* bsrc = bias + col0 + eseg * 32;
      const int v = (erow & 7) << 2;
      bf16_t ov[32];
#pragma unroll
      for (int a = 0; a < 8; ++a) {
        const f32x4 q4 = *(const f32x4*)(srow + (((eseg * 32) + a * 4) ^ v));
#pragma unroll
        for (int b = 0; b < 4; ++b)
          ov[a * 4 + b] = (bf16_t)gelu_fast(q4[b] + bsrc[a * 4 + b]);
      }
      bf16_t* dst = (bf16_t*)Cmat + (size_t)grow * Ncols + col0 + eseg * 32;
#pragma unroll
      for (int k = 0; k < 4; ++k)
        *(bf16x8*)(dst + k * 8) = *(bf16x8*)(ov + k * 8);
    }
    __syncthreads();
  }
}

// ---------------------------------------------------------------------------
// GEMM2 (R11-exact): 64x128 tile (M = 197*64 exact), 4 waves 2Mx2N (wave
// tile 32x64), BK=64, proven 2-phase gload_lds structure + 3-bit XOR swizzle.
// LDS 24.6KB; lb(256,5) (no spill: ~32 acc). BK=128 variant (R13) measured
// neutral; keeping the simpler BK=64 form from the session-best R11 run.
// Grid 1200 = 8 XCD x 150: two 4-XCD groups x 3 cols, col-fast per rband
// (W2eff 3-col group L2-resident).
// ---------------------------------------------------------------------------
__global__ __launch_bounds__(256, 5) void gemm2_kernel(
    const bf16_t* __restrict__ Amat, const bf16_t* __restrict__ Bmat,
    const float* __restrict__ bias, float* __restrict__ Cmat,
    int Mrows, int Ncols, int Kd) {
  __shared__ char smem[24576];
  bf16_t* lds = (bf16_t*)smem;   // A: elements [0,4096), B: [4096,12288)

  const int xcd = blockIdx.x & 7, t = blockIdx.x >> 3;   // t in [0,150)
  const int rowb = (t / 3) * 4 + (xcd & 3);
  if (rowb >= 197) return;
  const int colb = (xcd >> 2) * 3 + (t % 3);
  const int row0 = rowb * 64, col0 = colb * 128;

  const int tid = threadIdx.x, lane = tid & 63, wave = tid >> 6;
  const int wm = wave & 1, wn = wave >> 1;   // wm: 32-row half; wn: 64-col half

  // staging: A tile [64][64] = 512 chunks (2/thread), B [128][64] = 1024 (4/thread)
  const bf16_t* gA[2]; int ldsA[2];
  const bf16_t* gB[4]; int ldsB[4];
#pragma unroll
  for (int q = 0; q < 2; ++q) {
    int c = tid + q * 256;
    int r = c >> 3, kkg = (c & 7) ^ (r & 7);
    gA[q] = Amat + (size_t)(row0 + r) * Kd + kkg * 8;   // M exact, no clamp
    ldsA[q] = c * 16;
  }
#pragma unroll
  for (int q = 0; q < 4; ++q) {
    int c = tid + q * 256;
    int r = c >> 3, kkg = (c & 7) ^ (r & 7);
    gB[q] = Bmat + (size_t)(col0 + r) * Kd + kkg * 8;
    ldsB[q] = 8192 + c * 16;
  }

  const int rl = lane & 15, kc = lane >> 4;
  int aoffs[2], boffs[4];
#pragma unroll
  for (int i = 0; i < 2; ++i) {
    int ra = wm * 32 + i * 16 + rl;
    aoffs[i] = ra * 64 + ((kc ^ (ra & 7)) * 8);
  }
#pragma unroll
  for (int i = 0; i < 4; ++i) {
    int rb = wn * 64 + i * 16 + rl;
    boffs[i] = 4096 + rb * 64 + ((kc ^ (rb & 7)) * 8);
  }

  f32x4 acc[2][4] = {};
  const int iters = Kd / 64;   // 48

#pragma unroll
  for (int q = 0; q < 2; ++q) { gld16(gA[q], smem + ldsA[q]); gA[q] += 64; }
#pragma unroll
  for (int q = 0; q < 4; ++q) { gld16(gB[q], smem + ldsB[q]); gB[q] += 64; }
  __syncthreads();

  for (int it = 0; it < iters; ++it) {
#pragma unroll
    for (int ks = 0; ks < 2; ++ks) {
      bf16x8 af[2], bfr[4];
#pragma unroll
      for (int i = 0; i < 2; ++i) af[i] = *(const bf16x8*)(lds + (aoffs[i] ^ (ks * 32)));
#pragma unroll
      for (int i = 0; i < 4; ++i) bfr[i] = *(const bf16x8*)(lds + (boffs[i] ^ (ks * 32)));
#pragma unroll
      for (int mi = 0; mi < 2; ++mi)
#pragma unroll
        for (int ni = 0; ni < 4; ++ni)
          acc[mi][ni] = __builtin_amdgcn_mfma_f32_16x16x32_bf16(
              af[mi], bfr[ni], acc[mi][ni], 0, 0, 0);
    }
    if (it + 1 < iters) {
      __syncthreads();
#pragma unroll
      for (int q = 0; q < 2; ++q) { gld16(gA[q], smem + ldsA[q]); gA[q] += 64; }
#pragma unroll
      for (int q = 0; q < 4; ++q) { gld16(gB[q], smem + ldsB[q]); gB[q] += 64; }
      __syncthreads();
    }
  }

  // epilogue: f32 + bias, direct stores.
  const int crow = (lane >> 4) * 4, ccol = lane & 15;
#pragma unroll
  for (int ni = 0; ni < 4; ++ni) {
    const int gc = col0 + wn * 64 + ni * 16 + ccol;
    const float bv = bias[gc];
#pragma unroll
    for (int mi = 0; mi < 2; ++mi) {
      const int gr = row0 + wm * 32 + mi * 16 + crow;
#pragma unroll
      for (int r = 0; r < 4; ++r)
        Cmat[(size_t)(gr + r) * Ncols + gc] = acc[mi][ni][r] + bv;
    }
  }
}

extern "C" void kernel_launch(void* const* d_in, const int* in_sizes, int n_in,
                              void* d_out, int out_size, void* d_ws, size_t ws_size,
                              hipStream_t stream) {
  const float* x  = (const float*)d_in[0];
  const float* W1 = (const float*)d_in[1];
  const float* b1 = (const float*)d_in[2];
  const float* A1 = (const float*)d_in[3];
  const float* B1 = (const float*)d_in[4];
  const float* W2 = (const float*)d_in[5];
  const float* b2 = (const float*)d_in[6];
  const float* A2 = (const float*)d_in[7];
  const float* B2 = (const float*)d_in[8];
  float* out = (float*)d_out;

  char* ws = (char*)d_ws;
  bf16_t* xb    = (bf16_t*)ws;                             // 19,365,888 B (pad)
  bf16_t* W1eff = (bf16_t*)(ws + 19366144);                //  4,718,592 B
  bf16_t* W2eff = (bf16_t*)(ws + 19366144 + 4718592);      //  4,718,592 B
  bf16_t* hbuf  = (bf16_t*)(ws + 19366144 + 2 * 4718592);  // 77,463,552 B

  // 1 launch: cast + fold1 + fold2
  prep_kernel<<<CAST_BLOCKS + 2 * FOLD_BLOCKS, 256, 0, stream>>>(
      x, xb, W1, A1, B1, W1eff, W2, A2, B2, W2eff);

  // GEMM1: 99 rbands x 24 cols; per XCD 13 rbands, rband-fast -> grid 24*13*8
  gemm1_kernel<<<2496, 256, 0, stream>>>(
      xb, W1eff, b1, hbuf, M_ROWS, H_DIM, D_DIM);
  // GEMM2: 197 rbands x 6 cols; grid 8 XCD x 50 rband-strips x 3 cols = 1200
  gemm2_kernel<<<1200, 256, 0, stream>>>(
      hbuf, W2eff, b2, out, M_ROWS, D_DIM, H_DIM);
}